// Round 2
// baseline (1523.007 us; speedup 1.0000x reference)
//
#include <hip/hip_runtime.h>
#include <hip/hip_bf16.h>

// Problem: H=256, N=200000 sessions, U=20000 users.
// Runtime-detects whether float tensors are f32 or bf16, and whether
// user_ids is int64 or int32. Output dtype follows the float dtype.
#define HDIM 256
#define NROWS 200000
#define NUSERS 20000

// Harness-boilerplate symbol (defined, unused).
__global__ void UserSessionSimNet_21345987461278_kernel() {}

typedef __attribute__((ext_vector_type(8))) short bf16x8;  // 8 bf16 = 4 VGPRs
typedef __attribute__((ext_vector_type(4))) float f32x4;

__device__ __forceinline__ float b2f(__hip_bfloat16 v) { return __bfloat162float(v); }
__device__ __forceinline__ float bu2f(unsigned short u) {
  return __uint_as_float(((unsigned)u) << 16);
}

// Dual-dtype load: f32m!=0 -> float buffer, else bf16 buffer.
__device__ __forceinline__ float ldx(const void* p, int idx, int f32m) {
  if (f32m != 0) return ((const float*)p)[idx];
  return b2f(((const __hip_bfloat16*)p)[idx]);
}

// round-to-nearest-even bf16 of x, returned as f32 bits with low 16 zeroed
__device__ __forceinline__ unsigned bfr(float x) {
  unsigned u = __float_as_uint(x);
  return (u + 0x7FFFu + ((u >> 16) & 1u)) & 0xFFFF0000u;
}

// split f32 -> bf16 hi + bf16 lo (hi+lo represents x to ~2^-16 relative)
__device__ __forceinline__ void split_store(float x, __hip_bfloat16* h, __hip_bfloat16* l) {
  unsigned hb = bfr(x);
  float rem = x - __uint_as_float(hb);
  unsigned lb = bfr(rem);
  *(unsigned short*)h = (unsigned short)(hb >> 16);
  *(unsigned short*)l = (unsigned short)(lb >> 16);
}

// flags[0]=uid-is-int32, flags[1]=bf16 vote count, flags[2]=f32 mode
// ---- init ------------------------------------------------------------------
__global__ void k_init(int* counts, int* cursor, float* denom, int* segmaxB, int* flags) {
  int i = blockIdx.x * 256 + threadIdx.x;
  if (i < 3) flags[i] = 0;
  if (i < NUSERS) {
    counts[i] = 0;
    cursor[i] = 0;
    denom[i] = 0.0f;
    segmaxB[i] = (int)0xFF800000;  // -inf
  }
}

// ---- float dtype vote: bits[14:7] of each 32-bit word -----------------------
__global__ void k_dtype(const unsigned int* words, int* flags) {
  int i = blockIdx.x * 256 + threadIdx.x;  // 0..1023
  unsigned int f = (words[i] >> 7) & 0xFFu;
  if (f >= 100u && f <= 140u) atomicAdd(&flags[1], 1);
}

__global__ void k_flagfin(int* flags) {
  if (threadIdx.x == 0 && blockIdx.x == 0) {
    flags[2] = (flags[1] < 512) ? 1 : 0;  // few exponent-like hits -> f32
  }
}

// ---- user_ids dtype detect + convert ---------------------------------------
__global__ void k_detect(const int* raw, int* flags) {
  int i = blockIdx.x * 256 + threadIdx.x;  // 0..1023
  if (raw[2 * i + 1] != 0) atomicOr(&flags[0], 1);
}

__global__ void k_cvt(const int* raw, const int* flags, int* uid32) {
  int i = blockIdx.x * 256 + threadIdx.x;
  if (i >= NROWS) return;
  if (flags[0] != 0) {
    uid32[i] = raw[i];      // int32 data
  } else {
    uid32[i] = raw[2 * i];  // int64 data: low word
  }
}

// ---- pack: M = Wq*Wk^T, P = Wv*W1a^T, W1b^T; all stored B^T-layout [n][k]
//      as bf16 hi/lo splits for MFMA consumption ------------------------------
__global__ void k_pack(const void* Wq, const void* Wk, const void* Wv, const void* W1,
                       const int* flags,
                       __hip_bfloat16* pMT_hi, __hip_bfloat16* pMT_lo,
                       __hip_bfloat16* pPT_hi, __hip_bfloat16* pPT_lo,
                       __hip_bfloat16* pBT_hi, __hip_bfloat16* pBT_lo) {
  int a = blockIdx.x;   // k index
  int j = threadIdx.x;  // n index
  int f32m = flags[2];
  float accM = 0.0f, accP = 0.0f;
  for (int c = 0; c < HDIM; ++c) {
    float wq = ldx(Wq, a * HDIM + c, f32m);
    float wv = ldx(Wv, a * HDIM + c, f32m);
    float wk = ldx(Wk, j * HDIM + c, f32m);
    float w1 = ldx(W1, j * 2 * HDIM + c, f32m);
    accM += wq * wk;
    accP += wv * w1;
  }
  // B^T layout: [n=j][k=a]
  split_store(accM, &pMT_hi[j * HDIM + a], &pMT_lo[j * HDIM + a]);
  split_store(accP, &pPT_hi[j * HDIM + a], &pPT_lo[j * HDIM + a]);
  float w1b = ldx(W1, j * 2 * HDIM + HDIM + a, f32m);  // (W1b^T)[k=a][n=j]
  split_store(w1b, &pBT_hi[j * HDIM + a], &pBT_lo[j * HDIM + a]);
}

// ---- CSR build -------------------------------------------------------------
__global__ void k_hist(const int* uid, int* counts) {
  int i = blockIdx.x * 256 + threadIdx.x;
  if (i < NROWS) atomicAdd(&counts[uid[i]], 1);
}

__global__ void k_scan(const int* counts, int* offs) {
  __shared__ int partial[256];
  int t = threadIdx.x;
  const int CH = (NUSERS + 255) / 256;  // 79
  int s = 0;
  for (int k = 0; k < CH; ++k) {
    int i = t * CH + k;
    if (i < NUSERS) s += counts[i];
  }
  partial[t] = s;
  __syncthreads();
  if (t == 0) {
    int run = 0;
    for (int k = 0; k < 256; ++k) { int v = partial[k]; partial[k] = run; run += v; }
  }
  __syncthreads();
  int run = partial[t];
  for (int k = 0; k < CH; ++k) {
    int i = t * CH + k;
    if (i < NUSERS) { offs[i] = run; run += counts[i]; }
  }
}

__global__ void k_scatter(const int* uid, const int* offs, int* cursor, int* rows) {
  int i = blockIdx.x * 256 + threadIdx.x;
  if (i < NROWS) {
    int u = uid[i];
    int p = offs[u] + atomicAdd(&cursor[u], 1);
    rows[p] = i;
  }
}

// ---- MFMA GEMM core --------------------------------------------------------
// Per wave: 16 output rows x 256 cols via 16 col-tiles of 16x16, K=256.
// A frag (mfma_f32_16x16x32_bf16): lane l -> row = l&15, k = (l>>4)*8 + e
// B frag: lane l -> col = l&15, k = (l>>4)*8 + e  (read from B^T [n][k] layout)
// C/D:    lane l -> col = l&15, row = (l>>4)*4 + reg   [measured: learn_hip m89]
template <int F32M>
__device__ __forceinline__ void load_afrags(const void* A, int row, int kq,
                                            bf16x8* afr, bf16x8* alo) {
  if (F32M) {
    const float* ap = (const float*)A + row * HDIM + kq;
#pragma unroll
    for (int ks = 0; ks < 8; ++ks) {
      bf16x8 h, l;
#pragma unroll
      for (int e = 0; e < 8; ++e) {
        float x = ap[ks * 32 + e];
        unsigned hb = bfr(x);
        h[e] = (short)(hb >> 16);
        float rem = x - __uint_as_float(hb);
        l[e] = (short)(bfr(rem) >> 16);
      }
      afr[ks] = h;
      alo[ks] = l;
    }
  } else {
    const short* ap = (const short*)A + row * HDIM + kq;
#pragma unroll
    for (int ks = 0; ks < 8; ++ks) afr[ks] = *(const bf16x8*)(ap + ks * 32);
  }
}

// acc = A @ (B_hi + B_lo) [+ A_lo @ B_hi if F32M], one 16x16 tile, K=256
template <int F32M>
__device__ __forceinline__ f32x4 tile_acc(const bf16x8* afr, const bf16x8* alo,
                                          const short* bh, const short* bl) {
  f32x4 acc = {0.f, 0.f, 0.f, 0.f};
#pragma unroll
  for (int ks = 0; ks < 8; ++ks) {
    bf16x8 bhf = *(const bf16x8*)(bh + ks * 32);
    acc = __builtin_amdgcn_mfma_f32_16x16x32_bf16(afr[ks], bhf, acc, 0, 0, 0);
    bf16x8 blf = *(const bf16x8*)(bl + ks * 32);
    acc = __builtin_amdgcn_mfma_f32_16x16x32_bf16(afr[ks], blf, acc, 0, 0, 0);
    if (F32M)
      acc = __builtin_amdgcn_mfma_f32_16x16x32_bf16(alo[ks], bhf, acc, 0, 0, 0);
  }
  return acc;
}

// sim[r] = rowsum((Ue @ M) .* S); S prefetched to regs (hoisted off MFMA loop)
template <int F32M>
__global__ void __launch_bounds__(256) k_mm_sim_t(const void* Ue, const void* S,
    const __hip_bfloat16* pMT_hi, const __hip_bfloat16* pMT_lo,
    const int* flags, float* sim) {
  if (flags[2] != F32M) return;  // dual-instantiation dispatch on device flag
  const int lane = threadIdx.x & 63;
  const int rowBase = blockIdx.x * 64 + (threadIdx.x >> 6) * 16;
  const int r0 = lane & 15;
  const int kq = (lane >> 4) * 8;
  const int rgrp = rowBase + (lane >> 4) * 4;
  // ---- prefetch S values this lane will consume (16-lane groups read 32B
  //      contiguous chunks; issuing all 64 up front hides the HBM latency) ----
  float sv[16][4];
#pragma unroll
  for (int t = 0; t < 16; ++t)
#pragma unroll
    for (int g = 0; g < 4; ++g)
      sv[t][g] = ldx(S, (rgrp + g) * HDIM + t * 16 + r0, F32M);
  bf16x8 afr[8], alo[8];
  load_afrags<F32M>(Ue, rowBase + r0, kq, afr, alo);
  float psum0 = 0.f, psum1 = 0.f, psum2 = 0.f, psum3 = 0.f;
#pragma unroll
  for (int t = 0; t < 16; ++t) {
    const short* bh = (const short*)pMT_hi + (t * 16 + r0) * HDIM + kq;
    const short* bl = (const short*)pMT_lo + (t * 16 + r0) * HDIM + kq;
    f32x4 acc = tile_acc<F32M>(afr, alo, bh, bl);
    psum0 += acc[0] * sv[t][0];
    psum1 += acc[1] * sv[t][1];
    psum2 += acc[2] * sv[t][2];
    psum3 += acc[3] * sv[t][3];
  }
  // reduce across the 16 column-lanes of each group
#pragma unroll
  for (int off = 1; off < 16; off <<= 1) {
    psum0 += __shfl_xor(psum0, off);
    psum1 += __shfl_xor(psum1, off);
    psum2 += __shfl_xor(psum2, off);
    psum3 += __shfl_xor(psum3, off);
  }
  if (r0 == 0) {
    sim[rgrp + 0] = psum0;
    sim[rgrp + 1] = psum1;
    sim[rgrp + 2] = psum2;
    sim[rgrp + 3] = psum3;
  }
}

// Y[u] = wsum[u] @ W1b^T   (wsum bf16 exact, B split hi/lo); Y stored bf16
__global__ void __launch_bounds__(256) k_mm_y2(const __hip_bfloat16* wsum,
    const __hip_bfloat16* pBT_hi, const __hip_bfloat16* pBT_lo,
    unsigned short* Ybf) {
  const int lane = threadIdx.x & 63;
  const int rowBase = blockIdx.x * 64 + (threadIdx.x >> 6) * 16;
  if (rowBase >= NUSERS) return;
  const int r0 = lane & 15;
  const int kq = (lane >> 4) * 8;
  bf16x8 afr[8], alo[8];
  load_afrags<0>((const void*)wsum, rowBase + r0, kq, afr, alo);
  const int rgrp = rowBase + (lane >> 4) * 4;
#pragma unroll
  for (int t = 0; t < 16; ++t) {
    const short* bh = (const short*)pBT_hi + (t * 16 + r0) * HDIM + kq;
    const short* bl = (const short*)pBT_lo + (t * 16 + r0) * HDIM + kq;
    f32x4 acc = tile_acc<0>(afr, alo, bh, bl);
    int col = t * 16 + r0;
#pragma unroll
    for (int g = 0; g < 4; ++g)
      Ybf[(rgrp + g) * HDIM + col] = (unsigned short)(bfr(acc[g]) >> 16);
  }
}

// out[r] = relu(Ue[r] @ P + Y[uid[r]] + b1), dtype per flag.
// Y/bias prefetched to regs; output staged in LDS -> one coalesced copy
// (kills the 32B-partial-store read-modify-write seen in round 1 counters).
template <int F32M>
__global__ void __launch_bounds__(256) k_mm_out_t(const void* Ue,
    const __hip_bfloat16* pPT_hi, const __hip_bfloat16* pPT_lo,
    const int* uid, const unsigned short* Ybf, const void* b1,
    const int* flags, void* outv) {
  if (flags[2] != F32M) return;
  constexpr int ESZ = F32M ? 4 : 2;
  __shared__ __align__(16) char sOut[64 * HDIM * ESZ];  // 32KB bf16 / 64KB f32
  const int tid = threadIdx.x;
  const int lane = tid & 63;
  const int wave = tid >> 6;
  const int rowBase0 = blockIdx.x * 64;
  const int rowBase = rowBase0 + wave * 16;
  const int r0 = lane & 15;
  const int kq = (lane >> 4) * 8;
  const int rgrp = rowBase + (lane >> 4) * 4;
  const int lrow0 = wave * 16 + (lane >> 4) * 4;  // LDS row of g=0
  // ---- prefetch: uid -> Y rows (bf16, random gather hoisted) + bias --------
  int ug[4];
#pragma unroll
  for (int g = 0; g < 4; ++g) ug[g] = uid[rgrp + g];
  float yv[16][4];
#pragma unroll
  for (int t = 0; t < 16; ++t)
#pragma unroll
    for (int g = 0; g < 4; ++g)
      yv[t][g] = bu2f(Ybf[ug[g] * HDIM + t * 16 + r0]);
  float bv[16];
#pragma unroll
  for (int t = 0; t < 16; ++t) bv[t] = ldx(b1, t * 16 + r0, F32M);
  bf16x8 afr[8], alo[8];
  load_afrags<F32M>(Ue, rowBase + r0, kq, afr, alo);
#pragma unroll
  for (int t = 0; t < 16; ++t) {
    const short* bh = (const short*)pPT_hi + (t * 16 + r0) * HDIM + kq;
    const short* bl = (const short*)pPT_lo + (t * 16 + r0) * HDIM + kq;
    f32x4 acc = tile_acc<F32M>(afr, alo, bh, bl);
    int col = t * 16 + r0;
#pragma unroll
    for (int g = 0; g < 4; ++g) {
      float v = acc[g] + yv[t][g] + bv[t];
      if (!(v > 0.0f)) v = 0.0f;
      if (F32M)
        ((float*)sOut)[(lrow0 + g) * HDIM + col] = v;
      else
        ((unsigned short*)sOut)[(lrow0 + g) * HDIM + col] =
            (unsigned short)(bfr(v) >> 16);
    }
  }
  __syncthreads();
  // ---- coalesced tile store: full 128B lines, no RMW -----------------------
  const int NCH = 64 * HDIM * ESZ / 16;  // float4 chunks
  const float4* src = (const float4*)sOut;
  float4* dst = (float4*)((char*)outv + (size_t)rowBase0 * HDIM * ESZ);
#pragma unroll
  for (int c = 0; c < NCH / 256; ++c) dst[c * 256 + tid] = src[c * 256 + tid];
}

// ---- segment softmax -------------------------------------------------------
__global__ void k_segmax(const float* sim, const int* uid, int* segmaxB) {
  int i = blockIdx.x * 256 + threadIdx.x;
  if (i < NROWS) {
    float v = sim[i];
    int u = uid[i];
    if (v >= 0.0f)
      atomicMax(&segmaxB[u], __float_as_int(v));
    else
      atomicMin((unsigned int*)&segmaxB[u], __float_as_uint(v));
  }
}

__global__ void k_expdenom(const float* sim, const int* uid, const int* segmaxB,
                           float* e, float* denom) {
  int i = blockIdx.x * 256 + threadIdx.x;
  if (i < NROWS) {
    int u = uid[i];
    float m = __int_as_float(segmaxB[u]);
    float ev = __expf(sim[i] - m);
    e[i] = ev;
    atomicAdd(&denom[u], ev);
  }
}

// ---- weighted segment sum: wsum[u] = sum_i w_i * Ue[i]  (bf16 out) ---------
// Vector row loads (ushort4/float4) + index lookahead.
__global__ void k_wsum(const void* Ue, const int* offs, const int* counts,
                       const float* e, const float* denom, const int* rows,
                       const int* flags, __hip_bfloat16* wsum) {
  int u = blockIdx.x * 4 + (threadIdx.x >> 6);
  int lane = threadIdx.x & 63;
  if (u >= NUSERS) return;
  int off = offs[u], cnt = counts[u];
  int f32m = flags[2];
  float rd = 0.0f;
  if (cnt > 0) rd = 1.0f / denom[u];
  float a0 = 0.0f, a1 = 0.0f, a2 = 0.0f, a3 = 0.0f;
  int inext = (cnt > 0) ? rows[off] : 0;
  for (int j = 0; j < cnt; ++j) {
    int i = inext;
    if (j + 1 < cnt) inext = rows[off + j + 1];
    float w = e[i] * rd;
    if (f32m != 0) {
      float4 v = *(const float4*)((const float*)Ue + (size_t)i * HDIM + lane * 4);
      a0 += w * v.x;
      a1 += w * v.y;
      a2 += w * v.z;
      a3 += w * v.w;
    } else {
      ushort4 v = *(const ushort4*)((const unsigned short*)Ue + (size_t)i * HDIM + lane * 4);
      a0 += w * bu2f(v.x);
      a1 += w * bu2f(v.y);
      a2 += w * bu2f(v.z);
      a3 += w * bu2f(v.w);
    }
  }
  __hip_bfloat16* q = &wsum[u * HDIM + lane * 4];
  q[0] = __float2bfloat16(a0);
  q[1] = __float2bfloat16(a1);
  q[2] = __float2bfloat16(a2);
  q[3] = __float2bfloat16(a3);
}

extern "C" void kernel_launch(void* const* d_in, const int* in_sizes, int n_in,
                              void* d_out, int out_size, void* d_ws, size_t ws_size,
                              hipStream_t stream) {
  (void)in_sizes; (void)n_in; (void)out_size; (void)ws_size;
  const void* S  = d_in[0];
  const void* Ue = d_in[1];
  const int* uid_raw = (const int*)d_in[2];
  const void* Wq = d_in[3];
  const void* Wk = d_in[4];
  const void* Wv = d_in[5];
  const void* W1 = d_in[6];
  const void* b1 = d_in[7];

  char* w = (char*)d_ws;
  __hip_bfloat16* pMT_hi = (__hip_bfloat16*)(w + 0);        // 128 KB
  __hip_bfloat16* pMT_lo = (__hip_bfloat16*)(w + 131072);   // 128 KB
  __hip_bfloat16* pPT_hi = (__hip_bfloat16*)(w + 262144);   // 128 KB
  __hip_bfloat16* pPT_lo = (__hip_bfloat16*)(w + 393216);   // 128 KB
  __hip_bfloat16* pBT_hi = (__hip_bfloat16*)(w + 524288);   // 128 KB
  __hip_bfloat16* pBT_lo = (__hip_bfloat16*)(w + 655360);   // 128 KB
  float* sim    = (float*)(w + 786432);    // N*4
  float* e      = (float*)(w + 1586432);   // N*4
  int* segmaxB  = (int*)  (w + 2386432);   // U*4
  float* denom  = (float*)(w + 2466432);   // U*4
  int* counts   = (int*)  (w + 2546432);   // U*4
  int* cursor   = (int*)  (w + 2626432);   // U*4
  int* offs     = (int*)  (w + 2706432);   // U*4
  int* rows     = (int*)  (w + 2786432);   // N*4
  int* uid      = (int*)  (w + 3586432);   // N*4
  int* flags    = (int*)  (w + 4386432);   // 256 B
  __hip_bfloat16* wsum = (__hip_bfloat16*)(w + 4386688);      // U*H*2 = 10.24 MB
  unsigned short* Ybf  = (unsigned short*)(w + 14626688);     // U*H*2 = 10.24 MB

  k_init<<<(NUSERS + 255) / 256, 256, 0, stream>>>(counts, cursor, denom, segmaxB, flags);
  k_dtype<<<4, 256, 0, stream>>>((const unsigned int*)S, flags);
  k_flagfin<<<1, 64, 0, stream>>>(flags);
  k_detect<<<4, 256, 0, stream>>>(uid_raw, flags);
  k_cvt<<<(NROWS + 255) / 256, 256, 0, stream>>>(uid_raw, flags, uid);
  k_pack<<<HDIM, HDIM, 0, stream>>>(Wq, Wk, Wv, W1, flags,
                                    pMT_hi, pMT_lo, pPT_hi, pPT_lo, pBT_hi, pBT_lo);
  k_hist<<<(NROWS + 255) / 256, 256, 0, stream>>>(uid, counts);
  k_scan<<<1, 256, 0, stream>>>(counts, offs);
  k_scatter<<<(NROWS + 255) / 256, 256, 0, stream>>>(uid, offs, cursor, rows);
  // sim = rowsum((Ue @ M) .* S)   — MFMA, dual-dtype via device-flag dispatch
  k_mm_sim_t<0><<<NROWS / 64, 256, 0, stream>>>(Ue, S, pMT_hi, pMT_lo, flags, sim);
  k_mm_sim_t<1><<<NROWS / 64, 256, 0, stream>>>(Ue, S, pMT_hi, pMT_lo, flags, sim);
  k_segmax<<<(NROWS + 255) / 256, 256, 0, stream>>>(sim, uid, segmaxB);
  k_expdenom<<<(NROWS + 255) / 256, 256, 0, stream>>>(sim, uid, segmaxB, e, denom);
  k_wsum<<<(NUSERS + 3) / 4, 256, 0, stream>>>(Ue, offs, counts, e, denom, rows, flags, wsum);
  // Y = wsum @ W1b^T — MFMA, bf16 output (halves the out-kernel gather traffic)
  k_mm_y2<<<(NUSERS / 16 + 3) / 4, 256, 0, stream>>>(wsum, pBT_hi, pBT_lo, Ybf);
  // out = relu(Ue @ P + Y[uid] + b1) — MFMA, LDS-staged coalesced stores
  k_mm_out_t<0><<<NROWS / 64, 256, 0, stream>>>(Ue, pPT_hi, pPT_lo, uid, Ybf, b1, flags, d_out);
  k_mm_out_t<1><<<NROWS / 64, 256, 0, stream>>>(Ue, pPT_hi, pPT_lo, uid, Ybf, b1, flags, d_out);
}

// Round 3
// 1450.141 us; speedup vs baseline: 1.0502x; 1.0502x over previous
//
#include <hip/hip_runtime.h>
#include <hip/hip_bf16.h>

// Problem: H=256, N=200000 sessions, U=20000 users.
// Live mode (measured round 2): float tensors are f32, uid int64.
// Dual-dtype support retained via runtime-uniform branch (no dead launches).
#define HDIM 256
#define NROWS 200000
#define NUSERS 20000

// Harness-boilerplate symbol (defined, unused).
__global__ void UserSessionSimNet_21345987461278_kernel() {}

typedef __attribute__((ext_vector_type(8))) short bf16x8;  // 8 bf16 = 4 VGPRs
typedef __attribute__((ext_vector_type(4))) float f32x4;

__device__ __forceinline__ float b2f(__hip_bfloat16 v) { return __bfloat162float(v); }
__device__ __forceinline__ float bu2f(unsigned short u) {
  return __uint_as_float(((unsigned)u) << 16);
}

// Dual-dtype load: f32m!=0 -> float buffer, else bf16 buffer.
__device__ __forceinline__ float ldx(const void* p, int idx, int f32m) {
  if (f32m != 0) return ((const float*)p)[idx];
  return b2f(((const __hip_bfloat16*)p)[idx]);
}

// round-to-nearest-even bf16 of x, returned as f32 bits with low 16 zeroed
__device__ __forceinline__ unsigned bfr(float x) {
  unsigned u = __float_as_uint(x);
  return (u + 0x7FFFu + ((u >> 16) & 1u)) & 0xFFFF0000u;
}

// split f32 -> bf16 hi + bf16 lo (hi+lo represents x to ~2^-16 relative)
__device__ __forceinline__ void split_store(float x, __hip_bfloat16* h, __hip_bfloat16* l) {
  unsigned hb = bfr(x);
  float rem = x - __uint_as_float(hb);
  unsigned lb = bfr(rem);
  *(unsigned short*)h = (unsigned short)(hb >> 16);
  *(unsigned short*)l = (unsigned short)(lb >> 16);
}

// flags[0]=uid-is-int32, flags[1]=bf16 vote count, flags[2]=f32 mode
// ---- init ------------------------------------------------------------------
__global__ void k_init(int* counts, int* cursor, float* denom, int* segmaxB, int* flags) {
  int i = blockIdx.x * 256 + threadIdx.x;
  if (i < 3) flags[i] = 0;
  if (i < NUSERS) {
    counts[i] = 0;
    cursor[i] = 0;
    denom[i] = 0.0f;
    segmaxB[i] = (int)0xFF800000;  // -inf
  }
}

// ---- float dtype vote: bits[14:7] of each 32-bit word -----------------------
__global__ void k_dtype(const unsigned int* words, int* flags) {
  int i = blockIdx.x * 256 + threadIdx.x;  // 0..1023
  unsigned int f = (words[i] >> 7) & 0xFFu;
  if (f >= 100u && f <= 140u) atomicAdd(&flags[1], 1);
}

__global__ void k_flagfin(int* flags) {
  if (threadIdx.x == 0 && blockIdx.x == 0) {
    flags[2] = (flags[1] < 512) ? 1 : 0;  // few exponent-like hits -> f32
  }
}

// ---- user_ids dtype detect + convert ---------------------------------------
__global__ void k_detect(const int* raw, int* flags) {
  int i = blockIdx.x * 256 + threadIdx.x;  // 0..1023
  if (raw[2 * i + 1] != 0) atomicOr(&flags[0], 1);
}

__global__ void k_cvt(const int* raw, const int* flags, int* uid32) {
  int i = blockIdx.x * 256 + threadIdx.x;
  if (i >= NROWS) return;
  if (flags[0] != 0) {
    uid32[i] = raw[i];      // int32 data
  } else {
    uid32[i] = raw[2 * i];  // int64 data: low word
  }
}

// ---- pack: M = Wq*Wk^T, P = Wv*W1a^T, W1b^T; all stored B^T-layout [n][k]
//      as bf16 hi/lo splits for MFMA consumption ------------------------------
__global__ void k_pack(const void* Wq, const void* Wk, const void* Wv, const void* W1,
                       const int* flags,
                       __hip_bfloat16* pMT_hi, __hip_bfloat16* pMT_lo,
                       __hip_bfloat16* pPT_hi, __hip_bfloat16* pPT_lo,
                       __hip_bfloat16* pBT_hi, __hip_bfloat16* pBT_lo) {
  int a = blockIdx.x;   // k index
  int j = threadIdx.x;  // n index
  int f32m = flags[2];
  float accM = 0.0f, accP = 0.0f;
  for (int c = 0; c < HDIM; ++c) {
    float wq = ldx(Wq, a * HDIM + c, f32m);
    float wv = ldx(Wv, a * HDIM + c, f32m);
    float wk = ldx(Wk, j * HDIM + c, f32m);
    float w1 = ldx(W1, j * 2 * HDIM + c, f32m);
    accM += wq * wk;
    accP += wv * w1;
  }
  // B^T layout: [n=j][k=a]
  split_store(accM, &pMT_hi[j * HDIM + a], &pMT_lo[j * HDIM + a]);
  split_store(accP, &pPT_hi[j * HDIM + a], &pPT_lo[j * HDIM + a]);
  float w1b = ldx(W1, j * 2 * HDIM + HDIM + a, f32m);  // (W1b^T)[k=a][n=j]
  split_store(w1b, &pBT_hi[j * HDIM + a], &pBT_lo[j * HDIM + a]);
}

// ---- CSR build -------------------------------------------------------------
__global__ void k_hist(const int* uid, int* counts) {
  int i = blockIdx.x * 256 + threadIdx.x;
  if (i < NROWS) atomicAdd(&counts[uid[i]], 1);
}

__global__ void k_scan(const int* counts, int* offs) {
  __shared__ int partial[256];
  int t = threadIdx.x;
  const int CH = (NUSERS + 255) / 256;  // 79
  int s = 0;
  for (int k = 0; k < CH; ++k) {
    int i = t * CH + k;
    if (i < NUSERS) s += counts[i];
  }
  partial[t] = s;
  __syncthreads();
  if (t == 0) {
    int run = 0;
    for (int k = 0; k < 256; ++k) { int v = partial[k]; partial[k] = run; run += v; }
  }
  __syncthreads();
  int run = partial[t];
  for (int k = 0; k < CH; ++k) {
    int i = t * CH + k;
    if (i < NUSERS) { offs[i] = run; run += counts[i]; }
  }
}

__global__ void k_scatter(const int* uid, const int* offs, int* cursor, int* rows) {
  int i = blockIdx.x * 256 + threadIdx.x;
  if (i < NROWS) {
    int u = uid[i];
    int p = offs[u] + atomicAdd(&cursor[u], 1);
    rows[p] = i;
  }
}

// ---- MFMA GEMM core --------------------------------------------------------
// Per wave: 16 output rows x 256 cols via 16 col-tiles of 16x16, K=256.
// A frag (mfma_f32_16x16x32_bf16): lane l -> row = l&15, k = (l>>4)*8 + e
// B frag: lane l -> col = l&15, k = (l>>4)*8 + e  (read from B^T [n][k] layout)
// C/D:    lane l -> col = l&15, row = (l>>4)*4 + reg   [measured: learn_hip m89]
template <int F32M>
__device__ __forceinline__ void load_A(const void* A, int row, int kq,
                                       bf16x8* ah, bf16x8* al) {
  if (F32M) {
    const float4* ap = (const float4*)((const float*)A + (size_t)row * HDIM);
    float4 st[16];
#pragma unroll
    for (int ks = 0; ks < 8; ++ks) {
      st[2 * ks]     = ap[(kq >> 2) + ks * 8];
      st[2 * ks + 1] = ap[(kq >> 2) + ks * 8 + 1];
    }
#pragma unroll
    for (int ks = 0; ks < 8; ++ks) {
      bf16x8 h, l;
      const float* f = (const float*)&st[2 * ks];
#pragma unroll
      for (int e = 0; e < 8; ++e) {
        float x = f[e];
        unsigned hb = bfr(x);
        h[e] = (short)(hb >> 16);
        l[e] = (short)(bfr(x - __uint_as_float(hb)) >> 16);
      }
      ah[ks] = h;
      al[ks] = l;
    }
  } else {
    const short* ap = (const short*)A + (size_t)row * HDIM + kq;
#pragma unroll
    for (int ks = 0; ks < 8; ++ks) ah[ks] = *(const bf16x8*)(ap + ks * 32);
    // al untouched: never read on the F32M=0 path (dead).
  }
}

// acc = A_hi @ (B_hi + B_lo) [+ A_lo @ B_hi if F32M], one 16x16 tile, K=256
template <int F32M>
__device__ __forceinline__ f32x4 tile_acc(const bf16x8* ah, const bf16x8* al,
                                          const short* bh, const short* bl) {
  f32x4 acc = {0.f, 0.f, 0.f, 0.f};
#pragma unroll
  for (int ks = 0; ks < 8; ++ks) {
    bf16x8 bhf = *(const bf16x8*)(bh + ks * 32);
    acc = __builtin_amdgcn_mfma_f32_16x16x32_bf16(ah[ks], bhf, acc, 0, 0, 0);
    bf16x8 blf = *(const bf16x8*)(bl + ks * 32);
    acc = __builtin_amdgcn_mfma_f32_16x16x32_bf16(ah[ks], blf, acc, 0, 0, 0);
    if (F32M)
      acc = __builtin_amdgcn_mfma_f32_16x16x32_bf16(al[ks], bhf, acc, 0, 0, 0);
  }
  return acc;
}

// ---- sim = rowsum((Ue @ M) .* S), S via 2-tile-ahead rotating prefetch -----
template <int F32M>
__device__ __forceinline__ void sim_body(const void* Ue, const void* S,
    const short* mh, const short* ml, float* sim, int rowBase, int lane) {
  const int r0 = lane & 15;
  const int kq = (lane >> 4) * 8;
  const int rgrp = rowBase + (lane >> 4) * 4;
  bf16x8 ah[8], al[8];
  load_A<F32M>(Ue, rowBase + r0, kq, ah, al);
  float sv0[4], sv1[4], sv2[4];
#pragma unroll
  for (int g = 0; g < 4; ++g) sv0[g] = ldx(S, (rgrp + g) * HDIM + r0, F32M);
#pragma unroll
  for (int g = 0; g < 4; ++g) sv1[g] = ldx(S, (rgrp + g) * HDIM + 16 + r0, F32M);
  float ps0 = 0.f, ps1 = 0.f, ps2 = 0.f, ps3 = 0.f;
#pragma unroll
  for (int t = 0; t < 16; ++t) {
    if (t + 2 < 16) {
#pragma unroll
      for (int g = 0; g < 4; ++g)
        sv2[g] = ldx(S, (rgrp + g) * HDIM + (t + 2) * 16 + r0, F32M);
    }
    const short* bh = mh + (t * 16 + r0) * HDIM + kq;
    const short* bl = ml + (t * 16 + r0) * HDIM + kq;
    f32x4 acc = tile_acc<F32M>(ah, al, bh, bl);
    ps0 += acc[0] * sv0[0];
    ps1 += acc[1] * sv0[1];
    ps2 += acc[2] * sv0[2];
    ps3 += acc[3] * sv0[3];
#pragma unroll
    for (int g = 0; g < 4; ++g) { sv0[g] = sv1[g]; sv1[g] = sv2[g]; }
  }
#pragma unroll
  for (int off = 1; off < 16; off <<= 1) {
    ps0 += __shfl_xor(ps0, off);
    ps1 += __shfl_xor(ps1, off);
    ps2 += __shfl_xor(ps2, off);
    ps3 += __shfl_xor(ps3, off);
  }
  if (r0 == 0) {
    sim[rgrp + 0] = ps0;
    sim[rgrp + 1] = ps1;
    sim[rgrp + 2] = ps2;
    sim[rgrp + 3] = ps3;
  }
}

__global__ void __launch_bounds__(256) k_mm_sim2(const void* Ue, const void* S,
    const __hip_bfloat16* pMT_hi, const __hip_bfloat16* pMT_lo,
    const int* flags, float* sim) {
  const int lane = threadIdx.x & 63;
  const int rowBase = blockIdx.x * 64 + (threadIdx.x >> 6) * 16;
  if (flags[2])
    sim_body<1>(Ue, S, (const short*)pMT_hi, (const short*)pMT_lo, sim, rowBase, lane);
  else
    sim_body<0>(Ue, S, (const short*)pMT_hi, (const short*)pMT_lo, sim, rowBase, lane);
}

// ---- Y[u] = wsum[u] @ W1b^T (bf16 out); wave = column quarter --------------
__global__ void __launch_bounds__(256) k_mm_y3(const unsigned short* wsum,
    const __hip_bfloat16* pBT_hi, const __hip_bfloat16* pBT_lo,
    unsigned short* Ybf) {
  const int wave = threadIdx.x >> 6;
  const int lane = threadIdx.x & 63;
  const int rowBase = blockIdx.x * 16;  // grid = NUSERS/16 = 1250
  const int r0 = lane & 15;
  const int kq = (lane >> 4) * 8;
  bf16x8 ah[8], al[8];
  load_A<0>((const void*)wsum, rowBase + r0, kq, ah, al);
  const int rgrp = rowBase + (lane >> 4) * 4;
#pragma unroll
  for (int tt = 0; tt < 4; ++tt) {
    int t = wave * 4 + tt;
    const short* bh = (const short*)pBT_hi + (t * 16 + r0) * HDIM + kq;
    const short* bl = (const short*)pBT_lo + (t * 16 + r0) * HDIM + kq;
    f32x4 acc = tile_acc<0>(ah, al, bh, bl);
    int col = t * 16 + r0;
#pragma unroll
    for (int g = 0; g < 4; ++g)
      Ybf[(rgrp + g) * HDIM + col] = (unsigned short)(bfr(acc[g]) >> 16);
  }
}

// ---- out = relu(Ue @ P + Y[uid] + b1); Y/bias via rotating prefetch --------
template <int F32M>
__device__ __forceinline__ void out_body(const void* Ue,
    const short* ph, const short* pl, const int* uid,
    const unsigned short* Ybf, const void* b1, void* outv,
    int rowBase, int lane) {
  const int r0 = lane & 15;
  const int kq = (lane >> 4) * 8;
  const int rgrp = rowBase + (lane >> 4) * 4;
  int ug[4];
#pragma unroll
  for (int g = 0; g < 4; ++g) ug[g] = uid[rgrp + g];
  bf16x8 ah[8], al[8];
  load_A<F32M>(Ue, rowBase + r0, kq, ah, al);
  unsigned short yv0[4], yv1[4], yv2[4];
  float bv0, bv1, bv2;
#pragma unroll
  for (int g = 0; g < 4; ++g) yv0[g] = Ybf[ug[g] * HDIM + r0];
#pragma unroll
  for (int g = 0; g < 4; ++g) yv1[g] = Ybf[ug[g] * HDIM + 16 + r0];
  bv0 = ldx(b1, r0, F32M);
  bv1 = ldx(b1, 16 + r0, F32M);
  bv2 = 0.f;
#pragma unroll
  for (int t = 0; t < 16; ++t) {
    if (t + 2 < 16) {
#pragma unroll
      for (int g = 0; g < 4; ++g) yv2[g] = Ybf[ug[g] * HDIM + (t + 2) * 16 + r0];
      bv2 = ldx(b1, (t + 2) * 16 + r0, F32M);
    }
    const short* bh = ph + (t * 16 + r0) * HDIM + kq;
    const short* bl = pl + (t * 16 + r0) * HDIM + kq;
    f32x4 acc = tile_acc<F32M>(ah, al, bh, bl);
    int col = t * 16 + r0;
#pragma unroll
    for (int g = 0; g < 4; ++g) {
      float v = acc[g] + bu2f(yv0[g]) + bv0;
      if (!(v > 0.0f)) v = 0.0f;
      if (F32M)
        ((float*)outv)[(rgrp + g) * HDIM + col] = v;
      else
        ((unsigned short*)outv)[(rgrp + g) * HDIM + col] =
            (unsigned short)(bfr(v) >> 16);
    }
#pragma unroll
    for (int g = 0; g < 4; ++g) { yv0[g] = yv1[g]; yv1[g] = yv2[g]; }
    bv0 = bv1;
    bv1 = bv2;
  }
}

__global__ void __launch_bounds__(256) k_mm_out2(const void* Ue,
    const __hip_bfloat16* pPT_hi, const __hip_bfloat16* pPT_lo,
    const int* uid, const unsigned short* Ybf, const void* b1,
    const int* flags, void* outv) {
  const int lane = threadIdx.x & 63;
  const int rowBase = blockIdx.x * 64 + (threadIdx.x >> 6) * 16;
  if (flags[2])
    out_body<1>(Ue, (const short*)pPT_hi, (const short*)pPT_lo, uid, Ybf, b1, outv,
                rowBase, lane);
  else
    out_body<0>(Ue, (const short*)pPT_hi, (const short*)pPT_lo, uid, Ybf, b1, outv,
                rowBase, lane);
}

// ---- segment softmax -------------------------------------------------------
__global__ void k_segmax(const float* sim, const int* uid, int* segmaxB) {
  int i = blockIdx.x * 256 + threadIdx.x;
  if (i < NROWS) {
    float v = sim[i];
    int u = uid[i];
    if (v >= 0.0f)
      atomicMax(&segmaxB[u], __float_as_int(v));
    else
      atomicMin((unsigned int*)&segmaxB[u], __float_as_uint(v));
  }
}

__global__ void k_expdenom(const float* sim, const int* uid, const int* segmaxB,
                           float* e, float* denom) {
  int i = blockIdx.x * 256 + threadIdx.x;
  if (i < NROWS) {
    int u = uid[i];
    float m = __int_as_float(segmaxB[u]);
    float ev = __expf(sim[i] - m);
    e[i] = ev;
    atomicAdd(&denom[u], ev);
  }
}

// ---- weighted segment sum: wsum[u] = sum_i w_i * Ue[i]  (bf16 out) ---------
__global__ void k_wsum(const void* Ue, const int* offs, const int* counts,
                       const float* e, const float* denom, const int* rows,
                       const int* flags, __hip_bfloat16* wsum) {
  int u = blockIdx.x * 4 + (threadIdx.x >> 6);
  int lane = threadIdx.x & 63;
  if (u >= NUSERS) return;
  int off = offs[u], cnt = counts[u];
  int f32m = flags[2];
  float rd = 0.0f;
  if (cnt > 0) rd = 1.0f / denom[u];
  float a0 = 0.0f, a1 = 0.0f, a2 = 0.0f, a3 = 0.0f;
  int inext = (cnt > 0) ? rows[off] : 0;
  for (int j = 0; j < cnt; ++j) {
    int i = inext;
    if (j + 1 < cnt) inext = rows[off + j + 1];
    float w = e[i] * rd;
    if (f32m != 0) {
      float4 v = *(const float4*)((const float*)Ue + (size_t)i * HDIM + lane * 4);
      a0 += w * v.x;
      a1 += w * v.y;
      a2 += w * v.z;
      a3 += w * v.w;
    } else {
      ushort4 v = *(const ushort4*)((const unsigned short*)Ue + (size_t)i * HDIM + lane * 4);
      a0 += w * bu2f(v.x);
      a1 += w * bu2f(v.y);
      a2 += w * bu2f(v.z);
      a3 += w * bu2f(v.w);
    }
  }
  __hip_bfloat16* q = &wsum[u * HDIM + lane * 4];
  q[0] = __float2bfloat16(a0);
  q[1] = __float2bfloat16(a1);
  q[2] = __float2bfloat16(a2);
  q[3] = __float2bfloat16(a3);
}

extern "C" void kernel_launch(void* const* d_in, const int* in_sizes, int n_in,
                              void* d_out, int out_size, void* d_ws, size_t ws_size,
                              hipStream_t stream) {
  (void)in_sizes; (void)n_in; (void)out_size; (void)ws_size;
  const void* S  = d_in[0];
  const void* Ue = d_in[1];
  const int* uid_raw = (const int*)d_in[2];
  const void* Wq = d_in[3];
  const void* Wk = d_in[4];
  const void* Wv = d_in[5];
  const void* W1 = d_in[6];
  const void* b1 = d_in[7];

  char* w = (char*)d_ws;
  __hip_bfloat16* pMT_hi = (__hip_bfloat16*)(w + 0);        // 128 KB
  __hip_bfloat16* pMT_lo = (__hip_bfloat16*)(w + 131072);   // 128 KB
  __hip_bfloat16* pPT_hi = (__hip_bfloat16*)(w + 262144);   // 128 KB
  __hip_bfloat16* pPT_lo = (__hip_bfloat16*)(w + 393216);   // 128 KB
  __hip_bfloat16* pBT_hi = (__hip_bfloat16*)(w + 524288);   // 128 KB
  __hip_bfloat16* pBT_lo = (__hip_bfloat16*)(w + 655360);   // 128 KB
  float* sim    = (float*)(w + 786432);    // N*4
  float* e      = (float*)(w + 1586432);   // N*4
  int* segmaxB  = (int*)  (w + 2386432);   // U*4
  float* denom  = (float*)(w + 2466432);   // U*4
  int* counts   = (int*)  (w + 2546432);   // U*4
  int* cursor   = (int*)  (w + 2626432);   // U*4
  int* offs     = (int*)  (w + 2706432);   // U*4
  int* rows     = (int*)  (w + 2786432);   // N*4
  int* uid      = (int*)  (w + 3586432);   // N*4
  int* flags    = (int*)  (w + 4386432);   // 256 B
  __hip_bfloat16* wsum = (__hip_bfloat16*)(w + 4386688);      // U*H*2 = 10.24 MB
  unsigned short* Ybf  = (unsigned short*)(w + 14626688);     // U*H*2 = 10.24 MB

  k_init<<<(NUSERS + 255) / 256, 256, 0, stream>>>(counts, cursor, denom, segmaxB, flags);
  k_dtype<<<4, 256, 0, stream>>>((const unsigned int*)S, flags);
  k_flagfin<<<1, 64, 0, stream>>>(flags);
  k_detect<<<4, 256, 0, stream>>>(uid_raw, flags);
  k_cvt<<<(NROWS + 255) / 256, 256, 0, stream>>>(uid_raw, flags, uid);
  k_pack<<<HDIM, HDIM, 0, stream>>>(Wq, Wk, Wv, W1, flags,
                                    pMT_hi, pMT_lo, pPT_hi, pPT_lo, pBT_hi, pBT_lo);
  k_hist<<<(NROWS + 255) / 256, 256, 0, stream>>>(uid, counts);
  k_scan<<<1, 256, 0, stream>>>(counts, offs);
  k_scatter<<<(NROWS + 255) / 256, 256, 0, stream>>>(uid, offs, cursor, rows);
  // sim = rowsum((Ue @ M) .* S) — MFMA, runtime dtype branch (uniform)
  k_mm_sim2<<<NROWS / 64, 256, 0, stream>>>(Ue, S, pMT_hi, pMT_lo, flags, sim);
  k_segmax<<<(NROWS + 255) / 256, 256, 0, stream>>>(sim, uid, segmaxB);
  k_expdenom<<<(NROWS + 255) / 256, 256, 0, stream>>>(sim, uid, segmaxB, e, denom);
  k_wsum<<<(NUSERS + 3) / 4, 256, 0, stream>>>(Ue, offs, counts, e, denom, rows, flags, wsum);
  // Y = wsum @ W1b^T — MFMA, column-split waves for occupancy
  k_mm_y3<<<NUSERS / 16, 256, 0, stream>>>((const unsigned short*)wsum, pBT_hi, pBT_lo, Ybf);
  // out = relu(Ue @ P + Y[uid] + b1) — MFMA, direct stores, rotating prefetch
  k_mm_out2<<<NROWS / 64, 256, 0, stream>>>(Ue, pPT_hi, pPT_lo, uid, Ybf, b1, flags, d_out);
}